// Round 5
// baseline (1385.552 us; speedup 1.0000x reference)
//
#include <hip/hip_runtime.h>
#include <math.h>

#define VNUM 50000
#define OUTF 128
#define NEDGE 1600000
#define EPSF 1e-7f

#define BINV 4                      // vertices per bin
#define NBIN (VNUM / BINV)          // 12500
#define CONV_BLOCKS 12500           // 50000*64 words / 256
#define HIST_BLOCKS 6250            // 1600000 / 256
#define SCAN_BLOCKS 49              // ceil(12500/256)

// ---------------------------------------------------------------------------
// bf16 helpers (RNE)
// ---------------------------------------------------------------------------
__device__ __forceinline__ unsigned short f2bf(float f) {
    union { float f; unsigned int u; } c; c.f = f;
    unsigned int u = c.u;
    return (unsigned short)((u + 0x7FFFu + ((u >> 16) & 1u)) >> 16);
}
__device__ __forceinline__ float bf16_lo(unsigned int p) {
    union { unsigned int u; float f; } c; c.u = p << 16; return c.f;
}
__device__ __forceinline__ float bf16_hi(unsigned int p) {
    union { unsigned int u; float f; } c; c.u = p & 0xFFFF0000u; return c.f;
}

// 14-bit float (1s + 4e + 9m), covers |w| in [2^-14, 1]; rel err 2^-10.
__device__ __forceinline__ unsigned enc_w14(float w) {
    union { float f; unsigned u; } c; c.f = w;
    const unsigned u = c.u;
    const unsigned s = u >> 31;
    unsigned E = (u >> 23) & 0xFF;
    unsigned M = u & 0x7FFFFF;
    if (E < 113) return 0u;                 // flush |w| < 2^-14 (incl. 0)
    const unsigned Mr = M + (1u << 13);     // round mantissa to 9 bits
    E += (Mr >> 23);                        // carry (E<=127 after)
    M = Mr & 0x7FFFFF;
    return (s << 13) | ((E - 112) << 9) | (M >> 14);
}
__device__ __forceinline__ float dec_w14(unsigned w14) {
    const unsigned e = (w14 >> 9) & 0xF;
    union { unsigned u; float f; } c;
    c.u = ((w14 >> 13) << 31) | ((e + 112) << 23) | ((w14 & 0x1FF) << 14);
    return e ? c.f : 0.0f;
}

// ---------------------------------------------------------------------------
// prep: (a) vrepr f32 -> bf16x2, column-interleaved: word l = cols (l, l+64)
//       (b) per-bin histogram of tidx>>2
//       (c) weight transpose into d_ws
// ---------------------------------------------------------------------------
__global__ __launch_bounds__(256) void prep_kernel(
    const float* __restrict__ vrepr, unsigned int* __restrict__ vrepr16,
    const int* __restrict__ tidx, int* __restrict__ cnt,
    const float* __restrict__ loc_w, const float* __restrict__ std_w,
    float* wT)
{
    const int b = blockIdx.x, tid = threadIdx.x;
    if (b < CONV_BLOCKS) {
        const int idx = b * 256 + tid;          // word index, 0..3.2M-1
        const int v = idx >> 6, l = idx & 63;
        const float lo = vrepr[(size_t)v * 128 + l];
        const float hi = vrepr[(size_t)v * 128 + 64 + l];
        vrepr16[idx] = (unsigned)f2bf(lo) | ((unsigned)f2bf(hi) << 16);
    } else if (b < CONV_BLOCKS + HIST_BLOCKS) {
        const int e = (b - CONV_BLOCKS) * 256 + tid;
        atomicAdd(&cnt[tidx[e] >> 2], 1);
    } else {
        const int i = b - (CONV_BLOCKS + HIST_BLOCKS);  // 0..127
        const int h = i >> 6, kq = i & 63;
        const int k = kq * 2 + (tid >> 7);
        const int c = tid & 127;
        const float* w = h ? std_w : loc_w;
        wT[h * 16384 + k * 128 + c] = w[c * 128 + k];
    }
}

// ---------------------------------------------------------------------------
// 3-stage device-wide exclusive scan of cnt[NBIN] -> offs/cursor.
// ---------------------------------------------------------------------------
__device__ __forceinline__ int wave_incl_scan(int v, int lane) {
#pragma unroll
    for (int off = 1; off < 64; off <<= 1) {
        const int o = __shfl_up(v, off, 64);
        if (lane >= off) v += o;
    }
    return v;
}

__global__ __launch_bounds__(256) void scan_part_kernel(
    const int* __restrict__ cnt, int* __restrict__ partials)
{
    __shared__ int wsum[4];
    const int tid = threadIdx.x;
    const int i = blockIdx.x * 256 + tid;
    int v = (i < NBIN) ? cnt[i] : 0;
    const int lane = tid & 63, wave = tid >> 6;
#pragma unroll
    for (int off = 32; off > 0; off >>= 1) v += __shfl_down(v, off, 64);
    if (lane == 0) wsum[wave] = v;
    __syncthreads();
    if (tid == 0) partials[blockIdx.x] = wsum[0] + wsum[1] + wsum[2] + wsum[3];
}

__global__ __launch_bounds__(64) void scan_mid_kernel(
    const int* __restrict__ partials, int* __restrict__ blockoff,
    int* __restrict__ offs)
{
    const int tid = threadIdx.x;   // one wave
    const int v = (tid < SCAN_BLOCKS) ? partials[tid] : 0;
    const int inc = wave_incl_scan(v, tid);
    if (tid < SCAN_BLOCKS) blockoff[tid] = inc - v;   // exclusive
    if (tid == 63) offs[NBIN] = inc;                  // total == NEDGE
}

__global__ __launch_bounds__(256) void scan_final_kernel(
    const int* __restrict__ cnt, const int* __restrict__ blockoff,
    int* __restrict__ offs, int* __restrict__ cursor)
{
    __shared__ int wsum[4];
    const int tid = threadIdx.x;
    const int i = blockIdx.x * 256 + tid;
    const int v = (i < NBIN) ? cnt[i] : 0;
    const int lane = tid & 63, wave = tid >> 6;
    const int inc = wave_incl_scan(v, lane);
    if (lane == 63) wsum[wave] = inc;
    __syncthreads();
    int woff = blockoff[blockIdx.x];
    for (int w2 = 0; w2 < wave; ++w2) woff += wsum[w2];
    if (i < NBIN) {
        const int e = woff + inc - v;
        offs[i] = e; cursor[i] = e;
    }
}

// ---------------------------------------------------------------------------
// bucket: scatter one 4 B record per edge into its bin segment.
// record = sidx<<16 | w14<<2 | (tidx&3)
// ---------------------------------------------------------------------------
__global__ __launch_bounds__(256) void bucket_kernel(
    const int* __restrict__ sidx, const int* __restrict__ tidx,
    const float* __restrict__ enorm, const float* __restrict__ esgn,
    int* __restrict__ cursor, unsigned int* __restrict__ recs)
{
    const int e = blockIdx.x * 256 + threadIdx.x;
    const int t = tidx[e];
    const float w = esgn[e] * enorm[e];
    const int pos = atomicAdd(&cursor[t >> 2], 1);
    recs[pos] = ((unsigned)sidx[e] << 16) | (enc_w14(w) << 2) | (unsigned)(t & 3);
}

// ---------------------------------------------------------------------------
// aggregate: one block per bin (4 vertices). 4x128 f32 accumulator in LDS,
// ds_add_f32 no-return atomics (2-way banked = free). Lane l covers cols
// (l, l+64) matching the interleaved vrepr16 packing. Unroll 2 for MLP.
// ---------------------------------------------------------------------------
__global__ __launch_bounds__(256) void aggregate_kernel(
    const int* __restrict__ offs, const unsigned int* __restrict__ recs,
    const unsigned int* __restrict__ vrepr16, float* __restrict__ acc)
{
    __shared__ float lacc[BINV * OUTF];   // 2 KB
    const int bin = blockIdx.x;
    const int tid = threadIdx.x;
    lacc[tid] = 0.0f; lacc[tid + 256] = 0.0f;
    __syncthreads();

    const int lane = tid & 63, wv = tid >> 6;
    int i = offs[bin] + wv;
    const int end = offs[bin + 1];

    for (; i + 4 < end; i += 8) {          // 2 edges per iter per wave
        const unsigned rec0 = recs[i];
        const unsigned rec1 = recs[i + 4];
        const unsigned r0 = vrepr16[(size_t)(rec0 >> 16) * 64 + lane];
        const unsigned r1 = vrepr16[(size_t)(rec1 >> 16) * 64 + lane];
        const float w0 = dec_w14((rec0 >> 2) & 0x3FFF);
        const float w1 = dec_w14((rec1 >> 2) & 0x3FFF);
        const int lt0 = (rec0 & 3) * OUTF;
        const int lt1 = (rec1 & 3) * OUTF;
        unsafeAtomicAdd(&lacc[lt0 + lane],      bf16_lo(r0) * w0);
        unsafeAtomicAdd(&lacc[lt0 + 64 + lane], bf16_hi(r0) * w0);
        unsafeAtomicAdd(&lacc[lt1 + lane],      bf16_lo(r1) * w1);
        unsafeAtomicAdd(&lacc[lt1 + 64 + lane], bf16_hi(r1) * w1);
    }
    for (; i < end; i += 4) {
        const unsigned rec = recs[i];
        const unsigned r = vrepr16[(size_t)(rec >> 16) * 64 + lane];
        const float w = dec_w14((rec >> 2) & 0x3FFF);
        const int lt = (rec & 3) * OUTF;
        unsafeAtomicAdd(&lacc[lt + lane],      bf16_lo(r) * w);
        unsafeAtomicAdd(&lacc[lt + 64 + lane], bf16_hi(r) * w);
    }
    __syncthreads();

    if (tid < 128) {
        reinterpret_cast<float4*>(acc + (size_t)bin * BINV * OUTF)[tid] =
            reinterpret_cast<const float4*>(lacc)[tid];
    }
}

// ---------------------------------------------------------------------------
// gemm (coalesced-weights): transposed weights from d_ws. 32 rows per block.
// ---------------------------------------------------------------------------
__global__ __launch_bounds__(256) void gemm_wt_kernel(
    const float* acc, const float* __restrict__ wT,
    const float* __restrict__ loc_b, const float* __restrict__ std_b,
    float* out)
{
    __shared__ float tile[32][OUTF];   // 16 KB
    const int t = threadIdx.x;
    const int row0 = blockIdx.x * 32;

    {
        const float4* src = reinterpret_cast<const float4*>(acc + (size_t)row0 * OUTF);
        float4* dst = reinterpret_cast<float4*>(&tile[0][0]);
#pragma unroll
        for (int j = 0; j < 4; ++j) dst[t + 256 * j] = src[t + 256 * j];
    }
    __syncthreads();

    const int h    = t >> 7;
    const int half = (t >> 6) & 1;
    const int c0   = (t & 63) * 2;
    const float* wTh = wT + h * 16384;

    float acc0[16], acc1[16];
#pragma unroll
    for (int r = 0; r < 16; ++r) { acc0[r] = 0.0f; acc1[r] = 0.0f; }

    for (int kq = 0; kq < 32; ++kq) {
        const int k = kq * 4;
        const float2 wv0 = *reinterpret_cast<const float2*>(wTh + (size_t)(k + 0) * 128 + c0);
        const float2 wv1 = *reinterpret_cast<const float2*>(wTh + (size_t)(k + 1) * 128 + c0);
        const float2 wv2 = *reinterpret_cast<const float2*>(wTh + (size_t)(k + 2) * 128 + c0);
        const float2 wv3 = *reinterpret_cast<const float2*>(wTh + (size_t)(k + 3) * 128 + c0);
#pragma unroll
        for (int r = 0; r < 16; ++r) {
            const float4 pv = *reinterpret_cast<const float4*>(&tile[half * 16 + r][k]);
            acc0[r] = fmaf(pv.x, wv0.x, acc0[r]); acc1[r] = fmaf(pv.x, wv0.y, acc1[r]);
            acc0[r] = fmaf(pv.y, wv1.x, acc0[r]); acc1[r] = fmaf(pv.y, wv1.y, acc1[r]);
            acc0[r] = fmaf(pv.z, wv2.x, acc0[r]); acc1[r] = fmaf(pv.z, wv2.y, acc1[r]);
            acc0[r] = fmaf(pv.w, wv3.x, acc0[r]); acc1[r] = fmaf(pv.w, wv3.y, acc1[r]);
        }
    }

    const float* bb = h ? std_b : loc_b;
    const float b0 = bb[c0], b1 = bb[c0 + 1];
    float* dst = out + (h ? (size_t)VNUM * OUTF : (size_t)0);
#pragma unroll
    for (int r = 0; r < 16; ++r) {
        const int row = row0 + half * 16 + r;
        if (row < VNUM) {
            float x0 = acc0[r] + b0, x1 = acc1[r] + b1;
            if (h) {
                x0 = fmaxf(x0, 0.0f) + log1pf(expf(-fabsf(x0))) + EPSF;
                x1 = fmaxf(x1, 0.0f) + log1pf(expf(-fabsf(x1))) + EPSF;
            }
            *reinterpret_cast<float2*>(dst + (size_t)row * OUTF + c0) = make_float2(x0, x1);
        }
    }
}

// Fallback gemm (no workspace).
__global__ __launch_bounds__(256) void gemm_fallback_kernel(
    const float* acc,
    const float* __restrict__ loc_w, const float* __restrict__ loc_b,
    const float* __restrict__ std_w, const float* __restrict__ std_b,
    float* out)
{
    __shared__ float tile[16][OUTF];
    const int t = threadIdx.x;
    const int row0 = blockIdx.x * 16;
    {
        const float4* src = reinterpret_cast<const float4*>(acc + (size_t)row0 * OUTF);
        float4* dst = reinterpret_cast<float4*>(&tile[0][0]);
        dst[t] = src[t]; dst[t + 256] = src[t + 256];
    }
    __syncthreads();
    const int is_std = t >> 7;
    const int c = t & 127;
    const float* w = (is_std ? std_w : loc_w) + (size_t)c * OUTF;
    const float bias = is_std ? std_b[c] : loc_b[c];
    float accv[16];
#pragma unroll
    for (int r = 0; r < 16; ++r) accv[r] = 0.0f;
    for (int k = 0; k < OUTF; k += 4) {
        const float4 wv = *reinterpret_cast<const float4*>(w + k);
#pragma unroll
        for (int r = 0; r < 16; ++r) {
            const float4 pv = *reinterpret_cast<const float4*>(&tile[r][k]);
            float a = accv[r];
            a = fmaf(pv.x, wv.x, a); a = fmaf(pv.y, wv.y, a);
            a = fmaf(pv.z, wv.z, a); a = fmaf(pv.w, wv.w, a);
            accv[r] = a;
        }
    }
    float* dst_base = out + (is_std ? (size_t)VNUM * OUTF : (size_t)0);
#pragma unroll
    for (int r = 0; r < 16; ++r) {
        const float x = accv[r] + bias;
        dst_base[(size_t)(row0 + r) * OUTF + c] =
            is_std ? (fmaxf(x, 0.0f) + log1pf(expf(-fabsf(x))) + EPSF) : x;
    }
}

extern "C" void kernel_launch(void* const* d_in, const int* in_sizes, int n_in,
                              void* d_out, int out_size, void* d_ws, size_t ws_size,
                              hipStream_t stream) {
    const int*   sidx  = (const int*)  d_in[0];
    const int*   tidx  = (const int*)  d_in[1];
    const float* enorm = (const float*)d_in[2];
    const float* esgn  = (const float*)d_in[3];
    const float* vrepr = (const float*)d_in[4];
    const float* loc_w = (const float*)d_in[5];
    const float* loc_b = (const float*)d_in[6];
    const float* std_w = (const float*)d_in[7];
    const float* std_b = (const float*)d_in[8];

    float* out = (float*)d_out;
    float* acc = out;   // loc half doubles as segment-sum buffer

    // scratch in the std half of d_out:
    //   recs 1.6M | vrepr16 3.2M | cnt NBIN | offs NBIN+1 | cursor NBIN
    //   partials 49 | blockoff 49   total ~4.84M <= 6.4M words
    unsigned int* sbase   = (unsigned int*)(out + (size_t)VNUM * OUTF);
    unsigned int* recs    = sbase;
    unsigned int* vrepr16 = sbase + NEDGE;
    int* cnt      = (int*)(sbase + NEDGE + (size_t)VNUM * 64);
    int* offs     = cnt + NBIN;
    int* cursor   = offs + NBIN + 1;
    int* partials = cursor + NBIN;
    int* blockoff = partials + SCAN_BLOCKS;

    const bool use_ws = ws_size >= 2 * 16384 * sizeof(float);  // 128 KB for wT
    float* wT = use_ws ? (float*)d_ws : nullptr;

    hipMemsetAsync(cnt, 0, NBIN * sizeof(int), stream);

    const int prep_blocks = CONV_BLOCKS + HIST_BLOCKS + (use_ws ? 128 : 0);
    prep_kernel      <<<prep_blocks, 256, 0, stream>>>(vrepr, vrepr16, tidx, cnt,
                                                       loc_w, std_w, wT);
    scan_part_kernel <<<SCAN_BLOCKS, 256, 0, stream>>>(cnt, partials);
    scan_mid_kernel  <<<1,            64, 0, stream>>>(partials, blockoff, offs);
    scan_final_kernel<<<SCAN_BLOCKS, 256, 0, stream>>>(cnt, blockoff, offs, cursor);
    bucket_kernel    <<<NEDGE / 256, 256, 0, stream>>>(sidx, tidx, enorm, esgn,
                                                       cursor, recs);
    aggregate_kernel <<<NBIN,        256, 0, stream>>>(offs, recs, vrepr16, acc);

    if (use_ws) {
        gemm_wt_kernel<<<(VNUM + 31) / 32, 256, 0, stream>>>(acc, wT, loc_b, std_b, out);
    } else {
        gemm_fallback_kernel<<<VNUM / 16, 256, 0, stream>>>(acc, loc_w, loc_b,
                                                            std_w, std_b, out);
    }
}

// Round 6
// 388.884 us; speedup vs baseline: 3.5629x; 3.5629x over previous
//
#include <hip/hip_runtime.h>
#include <math.h>

#define VNUM 50000
#define OUTF 128
#define NEDGE 1600000
#define EPSF 1e-7f

#define CONV_BLOCKS 6250    // 50000*128 / (256*4)
#define HIST_BLOCKS 6250    // 1600000 / 256
#define SCAN_BLOCKS 196     // ceil(50000/256)

#define CHUNK 2048          // edges per coarse block
#define NCB 49              // coarse bins: tidx>>10
#define COARSE_BLOCKS 782   // ceil(NEDGE/CHUNK)

// ---------------------------------------------------------------------------
// bf16 helpers (RNE)
// ---------------------------------------------------------------------------
__device__ __forceinline__ unsigned short f2bf(float f) {
    union { float f; unsigned int u; } c; c.f = f;
    unsigned int u = c.u;
    return (unsigned short)((u + 0x7FFFu + ((u >> 16) & 1u)) >> 16);
}
__device__ __forceinline__ float bf16_lo(unsigned int p) {
    union { unsigned int u; float f; } c; c.u = p << 16; return c.f;
}
__device__ __forceinline__ float bf16_hi(unsigned int p) {
    union { unsigned int u; float f; } c; c.u = p & 0xFFFF0000u; return c.f;
}

// ---------------------------------------------------------------------------
// prep: (a) vrepr f32 -> packed bf16x2 (word i of row = cols 2i,2i+1)
//       (b) per-vertex histogram of tidx
//       (c) weight transpose into d_ws
// ---------------------------------------------------------------------------
__global__ __launch_bounds__(256) void prep_kernel(
    const float* __restrict__ vrepr, unsigned int* __restrict__ vrepr16,
    const int* __restrict__ tidx, int* __restrict__ cnt,
    const float* __restrict__ loc_w, const float* __restrict__ std_w,
    float* wT)
{
    const int b = blockIdx.x, tid = threadIdx.x;
    if (b < CONV_BLOCKS) {
        const size_t base = (size_t)b * 1024 + tid * 4;
        const float4 v = *reinterpret_cast<const float4*>(vrepr + base);
        uint2 o;
        o.x = (unsigned)f2bf(v.x) | ((unsigned)f2bf(v.y) << 16);
        o.y = (unsigned)f2bf(v.z) | ((unsigned)f2bf(v.w) << 16);
        *reinterpret_cast<uint2*>(vrepr16 + base / 2) = o;
    } else if (b < CONV_BLOCKS + HIST_BLOCKS) {
        const int e = (b - CONV_BLOCKS) * 256 + tid;
        atomicAdd(&cnt[tidx[e]], 1);
    } else {
        const int i = b - (CONV_BLOCKS + HIST_BLOCKS);  // 0..127
        const int h = i >> 6, kq = i & 63;
        const int k = kq * 2 + (tid >> 7);
        const int c = tid & 127;
        const float* w = h ? std_w : loc_w;
        wT[h * 16384 + k * 128 + c] = w[c * 128 + k];
    }
}

// ---------------------------------------------------------------------------
// 3-stage device-wide exclusive scan of cnt[VNUM] -> offs / fcursor / ccursor.
// ---------------------------------------------------------------------------
__device__ __forceinline__ int wave_incl_scan(int v, int lane) {
#pragma unroll
    for (int off = 1; off < 64; off <<= 1) {
        const int o = __shfl_up(v, off, 64);
        if (lane >= off) v += o;
    }
    return v;
}

__global__ __launch_bounds__(256) void scan_part_kernel(
    const int* __restrict__ cnt, int* __restrict__ partials)
{
    __shared__ int wsum[4];
    const int tid = threadIdx.x;
    const int i = blockIdx.x * 256 + tid;
    int v = (i < VNUM) ? cnt[i] : 0;
    const int lane = tid & 63, wave = tid >> 6;
#pragma unroll
    for (int off = 32; off > 0; off >>= 1) v += __shfl_down(v, off, 64);
    if (lane == 0) wsum[wave] = v;
    __syncthreads();
    if (tid == 0) partials[blockIdx.x] = wsum[0] + wsum[1] + wsum[2] + wsum[3];
}

__global__ __launch_bounds__(256) void scan_mid_kernel(
    const int* __restrict__ partials, int* __restrict__ blockoff,
    int* __restrict__ offs)
{
    __shared__ int wsum[4];
    const int tid = threadIdx.x;
    int v = (tid < SCAN_BLOCKS) ? partials[tid] : 0;
    const int lane = tid & 63, wave = tid >> 6;
    int inc = wave_incl_scan(v, lane);
    if (lane == 63) wsum[wave] = inc;
    __syncthreads();
    int woff = 0;
    for (int w2 = 0; w2 < wave; ++w2) woff += wsum[w2];
    if (tid < SCAN_BLOCKS) blockoff[tid] = woff + inc - v;
    if (tid == 0) offs[VNUM] = wsum[0] + wsum[1] + wsum[2] + wsum[3]; // NEDGE
}

__global__ __launch_bounds__(256) void scan_final_kernel(
    const int* __restrict__ cnt, const int* __restrict__ blockoff,
    int* __restrict__ offs, int* __restrict__ fcursor, int* __restrict__ ccursor)
{
    __shared__ int wsum[4];
    const int tid = threadIdx.x;
    const int i = blockIdx.x * 256 + tid;
    const int v = (i < VNUM) ? cnt[i] : 0;
    const int lane = tid & 63, wave = tid >> 6;
    const int inc = wave_incl_scan(v, lane);
    if (lane == 63) wsum[wave] = inc;
    __syncthreads();
    int woff = blockoff[blockIdx.x];
    for (int w2 = 0; w2 < wave; ++w2) woff += wsum[w2];
    if (i < VNUM) {
        const int e = woff + inc - v;
        offs[i] = e; fcursor[i] = e;
        if ((i & 1023) == 0) ccursor[i >> 10] = e;   // coarse segment start
    }
}

// ---------------------------------------------------------------------------
// Pass A: coarse partition. Each block stages CHUNK edges in LDS binned by
// tidx>>10 (per-wave replicated int counters -> low LDS-atomic contention),
// bulk-reserves one global run per bin, writes contiguous ~340 B runs.
// rec = { sidx<<16 | bf16(w), tidx }
// ---------------------------------------------------------------------------
__global__ __launch_bounds__(256) void coarse_kernel(
    const int* __restrict__ sidx, const int* __restrict__ tidx,
    const float* __restrict__ enorm, const float* __restrict__ esgn,
    int* __restrict__ ccursor, uint2* __restrict__ coarse8)
{
    __shared__ uint2 lrec[CHUNK];      // 16 KB
    __shared__ int lcnt[4][NCB];
    __shared__ int lbase[4][NCB];
    __shared__ int loffs[NCB];
    __shared__ int grun[NCB];

    const int tid = threadIdx.x, lane = tid & 63, wv = tid >> 6;
    const int base = blockIdx.x * CHUNK;
    const int n = min(CHUNK, NEDGE - base);

    for (int i = tid; i < 4 * NCB; i += 256) (&lcnt[0][0])[i] = 0;
    __syncthreads();

    uint2 rec[8];
#pragma unroll
    for (int j = 0; j < 8; ++j) {
        const int e = base + j * 256 + tid;
        if (e < NEDGE) {
            const int t = tidx[e];
            const float w = esgn[e] * enorm[e];
            rec[j].x = ((unsigned)sidx[e] << 16) | (unsigned)f2bf(w);
            rec[j].y = (unsigned)t;
            atomicAdd(&lcnt[wv][t >> 10], 1);
        }
    }
    __syncthreads();

    if (tid < 64) {
        int c0 = 0, c1 = 0, c2 = 0, c3 = 0, tot = 0;
        if (lane < NCB) {
            c0 = lcnt[0][lane]; c1 = lcnt[1][lane];
            c2 = lcnt[2][lane]; c3 = lcnt[3][lane];
            tot = c0 + c1 + c2 + c3;
        }
        const int inc = wave_incl_scan(tot, lane);
        const int ex = inc - tot;
        if (lane < NCB) {
            loffs[lane]    = ex;
            lbase[0][lane] = ex;
            lbase[1][lane] = ex + c0;
            lbase[2][lane] = ex + c0 + c1;
            lbase[3][lane] = ex + c0 + c1 + c2;
            grun[lane] = atomicAdd(&ccursor[lane], tot);
        }
    }
    __syncthreads();

#pragma unroll
    for (int j = 0; j < 8; ++j) {
        const int e = base + j * 256 + tid;
        if (e < NEDGE) {
            const int cb = (int)(rec[j].y >> 10);
            const int pos = atomicAdd(&lbase[wv][cb], 1);
            lrec[pos] = rec[j];
        }
    }
    __syncthreads();

    for (int i = tid; i < n; i += 256) {
        const uint2 r = lrec[i];
        const int cb = (int)(r.y >> 10);
        coarse8[grun[cb] + (i - loffs[cb])] = r;
    }
}

// ---------------------------------------------------------------------------
// Pass B: fine scatter within ~130 KB coarse-bin windows (L2-resident).
// ---------------------------------------------------------------------------
__global__ __launch_bounds__(256) void fine_kernel(
    const uint2* __restrict__ coarse8, int* __restrict__ fcursor,
    unsigned int* __restrict__ pairs)
{
    const int i = blockIdx.x * 256 + threadIdx.x;
    const uint2 r = coarse8[i];
    const int pos = atomicAdd(&fcursor[(int)r.y], 1);
    pairs[pos] = r.x;
}

// ---------------------------------------------------------------------------
// aggregate (R4-proven): one wave per vertex, lane covers cols (2l, 2l+1).
// 256 B coalesced bf16-row gathers, unroll-4, float2 store.
// ---------------------------------------------------------------------------
__global__ __launch_bounds__(256) void aggregate_kernel(
    const int* __restrict__ offs, const unsigned int* __restrict__ pairs,
    const unsigned int* __restrict__ vrepr16, float* __restrict__ acc)
{
    const int v = blockIdx.x * 4 + (threadIdx.x >> 6);
    const int l = threadIdx.x & 63;
    int i = offs[v];
    const int end = offs[v + 1];

    float a0 = 0.0f, a1 = 0.0f;
    for (; i + 4 <= end; i += 4) {
        const unsigned p0 = pairs[i], p1 = pairs[i + 1];
        const unsigned p2 = pairs[i + 2], p3 = pairs[i + 3];
        const unsigned r0 = vrepr16[(size_t)(p0 >> 16) * 64 + l];
        const unsigned r1 = vrepr16[(size_t)(p1 >> 16) * 64 + l];
        const unsigned r2 = vrepr16[(size_t)(p2 >> 16) * 64 + l];
        const unsigned r3 = vrepr16[(size_t)(p3 >> 16) * 64 + l];
        const float w0 = bf16_lo(p0), w1 = bf16_lo(p1);
        const float w2 = bf16_lo(p2), w3 = bf16_lo(p3);
        a0 = fmaf(bf16_lo(r0), w0, a0); a1 = fmaf(bf16_hi(r0), w0, a1);
        a0 = fmaf(bf16_lo(r1), w1, a0); a1 = fmaf(bf16_hi(r1), w1, a1);
        a0 = fmaf(bf16_lo(r2), w2, a0); a1 = fmaf(bf16_hi(r2), w2, a1);
        a0 = fmaf(bf16_lo(r3), w3, a0); a1 = fmaf(bf16_hi(r3), w3, a1);
    }
    for (; i < end; ++i) {
        const unsigned p = pairs[i];
        const unsigned r = vrepr16[(size_t)(p >> 16) * 64 + l];
        const float w = bf16_lo(p);
        a0 = fmaf(bf16_lo(r), w, a0); a1 = fmaf(bf16_hi(r), w, a1);
    }
    *reinterpret_cast<float2*>(acc + (size_t)v * OUTF + 2 * l) = make_float2(a0, a1);
}

// ---------------------------------------------------------------------------
// gemm (coalesced-weights): transposed weights from d_ws. 32 rows per block.
// ---------------------------------------------------------------------------
__global__ __launch_bounds__(256) void gemm_wt_kernel(
    const float* acc, const float* __restrict__ wT,
    const float* __restrict__ loc_b, const float* __restrict__ std_b,
    float* out)
{
    __shared__ float tile[32][OUTF];   // 16 KB
    const int t = threadIdx.x;
    const int row0 = blockIdx.x * 32;

    {
        const float4* src = reinterpret_cast<const float4*>(acc + (size_t)row0 * OUTF);
        float4* dst = reinterpret_cast<float4*>(&tile[0][0]);
#pragma unroll
        for (int j = 0; j < 4; ++j) dst[t + 256 * j] = src[t + 256 * j];
    }
    __syncthreads();

    const int h    = t >> 7;
    const int half = (t >> 6) & 1;
    const int c0   = (t & 63) * 2;
    const float* wTh = wT + h * 16384;

    float acc0[16], acc1[16];
#pragma unroll
    for (int r = 0; r < 16; ++r) { acc0[r] = 0.0f; acc1[r] = 0.0f; }

    for (int kq = 0; kq < 32; ++kq) {
        const int k = kq * 4;
        const float2 wv0 = *reinterpret_cast<const float2*>(wTh + (size_t)(k + 0) * 128 + c0);
        const float2 wv1 = *reinterpret_cast<const float2*>(wTh + (size_t)(k + 1) * 128 + c0);
        const float2 wv2 = *reinterpret_cast<const float2*>(wTh + (size_t)(k + 2) * 128 + c0);
        const float2 wv3 = *reinterpret_cast<const float2*>(wTh + (size_t)(k + 3) * 128 + c0);
#pragma unroll
        for (int r = 0; r < 16; ++r) {
            const float4 pv = *reinterpret_cast<const float4*>(&tile[half * 16 + r][k]);
            acc0[r] = fmaf(pv.x, wv0.x, acc0[r]); acc1[r] = fmaf(pv.x, wv0.y, acc1[r]);
            acc0[r] = fmaf(pv.y, wv1.x, acc0[r]); acc1[r] = fmaf(pv.y, wv1.y, acc1[r]);
            acc0[r] = fmaf(pv.z, wv2.x, acc0[r]); acc1[r] = fmaf(pv.z, wv2.y, acc1[r]);
            acc0[r] = fmaf(pv.w, wv3.x, acc0[r]); acc1[r] = fmaf(pv.w, wv3.y, acc1[r]);
        }
    }

    const float* bb = h ? std_b : loc_b;
    const float b0 = bb[c0], b1 = bb[c0 + 1];
    float* dst = out + (h ? (size_t)VNUM * OUTF : (size_t)0);
#pragma unroll
    for (int r = 0; r < 16; ++r) {
        const int row = row0 + half * 16 + r;
        if (row < VNUM) {
            float x0 = acc0[r] + b0, x1 = acc1[r] + b1;
            if (h) {
                x0 = fmaxf(x0, 0.0f) + log1pf(expf(-fabsf(x0))) + EPSF;
                x1 = fmaxf(x1, 0.0f) + log1pf(expf(-fabsf(x1))) + EPSF;
            }
            *reinterpret_cast<float2*>(dst + (size_t)row * OUTF + c0) = make_float2(x0, x1);
        }
    }
}

// Fallback gemm (no workspace).
__global__ __launch_bounds__(256) void gemm_fallback_kernel(
    const float* acc,
    const float* __restrict__ loc_w, const float* __restrict__ loc_b,
    const float* __restrict__ std_w, const float* __restrict__ std_b,
    float* out)
{
    __shared__ float tile[16][OUTF];
    const int t = threadIdx.x;
    const int row0 = blockIdx.x * 16;
    {
        const float4* src = reinterpret_cast<const float4*>(acc + (size_t)row0 * OUTF);
        float4* dst = reinterpret_cast<float4*>(&tile[0][0]);
        dst[t] = src[t]; dst[t + 256] = src[t + 256];
    }
    __syncthreads();
    const int is_std = t >> 7;
    const int c = t & 127;
    const float* w = (is_std ? std_w : loc_w) + (size_t)c * OUTF;
    const float bias = is_std ? std_b[c] : loc_b[c];
    float accv[16];
#pragma unroll
    for (int r = 0; r < 16; ++r) accv[r] = 0.0f;
    for (int k = 0; k < OUTF; k += 4) {
        const float4 wv = *reinterpret_cast<const float4*>(w + k);
#pragma unroll
        for (int r = 0; r < 16; ++r) {
            const float4 pv = *reinterpret_cast<const float4*>(&tile[r][k]);
            float a = accv[r];
            a = fmaf(pv.x, wv.x, a); a = fmaf(pv.y, wv.y, a);
            a = fmaf(pv.z, wv.z, a); a = fmaf(pv.w, wv.w, a);
            accv[r] = a;
        }
    }
    float* dst_base = out + (is_std ? (size_t)VNUM * OUTF : (size_t)0);
#pragma unroll
    for (int r = 0; r < 16; ++r) {
        const float x = accv[r] + bias;
        dst_base[(size_t)(row0 + r) * OUTF + c] =
            is_std ? (fmaxf(x, 0.0f) + log1pf(expf(-fabsf(x))) + EPSF) : x;
    }
}

extern "C" void kernel_launch(void* const* d_in, const int* in_sizes, int n_in,
                              void* d_out, int out_size, void* d_ws, size_t ws_size,
                              hipStream_t stream) {
    const int*   sidx  = (const int*)  d_in[0];
    const int*   tidx  = (const int*)  d_in[1];
    const float* enorm = (const float*)d_in[2];
    const float* esgn  = (const float*)d_in[3];
    const float* vrepr = (const float*)d_in[4];
    const float* loc_w = (const float*)d_in[5];
    const float* loc_b = (const float*)d_in[6];
    const float* std_w = (const float*)d_in[7];
    const float* std_b = (const float*)d_in[8];

    float* out = (float*)d_out;
    float* acc = out;   // loc half: coarse8 first, then segment sums (acc)

    // coarse8 (12.8 MB) borrows the loc half; dead before aggregate writes acc.
    uint2* coarse8 = (uint2*)out;

    // std-half scratch: pairs 1.6M | vrepr16 3.2M | cnt 50K | offs 50K+1 |
    // fcursor 50K | ccursor 49 | partials 196 | blockoff 196  (~4.95M words)
    unsigned int* sbase   = (unsigned int*)(out + (size_t)VNUM * OUTF);
    unsigned int* pairs   = sbase;
    unsigned int* vrepr16 = sbase + NEDGE;
    int* cnt      = (int*)(sbase + NEDGE + (size_t)VNUM * 64);
    int* offs     = cnt + VNUM;
    int* fcursor  = offs + VNUM + 1;
    int* ccursor  = fcursor + VNUM;
    int* partials = ccursor + NCB;
    int* blockoff = partials + SCAN_BLOCKS;

    const bool use_ws = ws_size >= 2 * 16384 * sizeof(float);  // 128 KB
    float* wT = use_ws ? (float*)d_ws : nullptr;

    hipMemsetAsync(cnt, 0, VNUM * sizeof(int), stream);

    const int prep_blocks = CONV_BLOCKS + HIST_BLOCKS + (use_ws ? 128 : 0);
    prep_kernel      <<<prep_blocks, 256, 0, stream>>>(vrepr, vrepr16, tidx, cnt,
                                                       loc_w, std_w, wT);
    scan_part_kernel <<<SCAN_BLOCKS, 256, 0, stream>>>(cnt, partials);
    scan_mid_kernel  <<<1,           256, 0, stream>>>(partials, blockoff, offs);
    scan_final_kernel<<<SCAN_BLOCKS, 256, 0, stream>>>(cnt, blockoff, offs,
                                                       fcursor, ccursor);
    coarse_kernel    <<<COARSE_BLOCKS, 256, 0, stream>>>(sidx, tidx, enorm, esgn,
                                                         ccursor, coarse8);
    fine_kernel      <<<NEDGE / 256, 256, 0, stream>>>(coarse8, fcursor, pairs);
    aggregate_kernel <<<VNUM / 4,    256, 0, stream>>>(offs, pairs, vrepr16, acc);

    if (use_ws) {
        gemm_wt_kernel<<<(VNUM + 31) / 32, 256, 0, stream>>>(acc, wT, loc_b, std_b, out);
    } else {
        gemm_fallback_kernel<<<VNUM / 16, 256, 0, stream>>>(acc, loc_w, loc_b,
                                                            std_w, std_b, out);
    }
}

// Round 7
// 349.451 us; speedup vs baseline: 3.9649x; 1.1128x over previous
//
#include <hip/hip_runtime.h>
#include <math.h>

#define VNUM 50000
#define OUTF 128
#define NEDGE 1600000
#define EPSF 1e-7f

#define CONV_BLOCKS 6250    // 50000*128 / (256*4)
#define HIST_BLOCKS 6250    // 1600000 / 256
#define BFRAG_BLOCKS 64     // 16384 uint pairs / 256
#define SCAN_BLOCKS 196     // ceil(50000/256)

#define CHUNK 2048          // edges per coarse block
#define NCB 49              // coarse bins: tidx>>10
#define COARSE_BLOCKS 782   // ceil(NEDGE/CHUNK)

typedef __attribute__((ext_vector_type(8))) short short8;
typedef __attribute__((ext_vector_type(4))) float v4f;

// ---------------------------------------------------------------------------
// bf16 helpers (RNE)
// ---------------------------------------------------------------------------
__device__ __forceinline__ unsigned short f2bf(float f) {
    union { float f; unsigned int u; } c; c.f = f;
    unsigned int u = c.u;
    return (unsigned short)((u + 0x7FFFu + ((u >> 16) & 1u)) >> 16);
}
__device__ __forceinline__ float bf16_lo(unsigned int p) {
    union { unsigned int u; float f; } c; c.u = p << 16; return c.f;
}
__device__ __forceinline__ float bf16_hi(unsigned int p) {
    union { unsigned int u; float f; } c; c.u = p & 0xFFFF0000u; return c.f;
}

// ---------------------------------------------------------------------------
// prep: (a) vrepr f32 -> packed bf16x2 (word i of row = cols 2i,2i+1)
//       (b) per-vertex histogram of tidx
//       (c) MFMA B-fragment build (both heads, bf16) into d_ws
// B[k][n] = w_h[c][k] with n = ct*16 + (lane&15), k = ks*32 + (lane>>4)*8 + j.
// Flat pair index p = ((ct*4+ks)*64 + lane)*4 + j2  (j = 2*j2, j2+1).
// ---------------------------------------------------------------------------
__global__ __launch_bounds__(256) void prep_kernel(
    const float* __restrict__ vrepr, unsigned int* __restrict__ vrepr16,
    const int* __restrict__ tidx, int* __restrict__ cnt,
    const float* __restrict__ loc_w, const float* __restrict__ std_w,
    unsigned int* bfrag)
{
    const int b = blockIdx.x, tid = threadIdx.x;
    if (b < CONV_BLOCKS) {
        const size_t base = (size_t)b * 1024 + tid * 4;
        const float4 v = *reinterpret_cast<const float4*>(vrepr + base);
        uint2 o;
        o.x = (unsigned)f2bf(v.x) | ((unsigned)f2bf(v.y) << 16);
        o.y = (unsigned)f2bf(v.z) | ((unsigned)f2bf(v.w) << 16);
        *reinterpret_cast<uint2*>(vrepr16 + base / 2) = o;
    } else if (b < CONV_BLOCKS + HIST_BLOCKS) {
        const int e = (b - CONV_BLOCKS) * 256 + tid;
        atomicAdd(&cnt[tidx[e]], 1);
    } else {
        const int p = (b - (CONV_BLOCKS + HIST_BLOCKS)) * 256 + tid; // 0..16383
        const int j2 = p & 3, lq = (p >> 2) & 63, ks = (p >> 8) & 3, ct = p >> 10;
        const int k = ks * 32 + (lq >> 4) * 8 + j2 * 2;
        const int n = ct * 16 + (lq & 15);
        const float* wsrc = (n >> 7) ? std_w : loc_w;
        const int c = n & 127;
        bfrag[p] = (unsigned)f2bf(wsrc[c * 128 + k]) |
                   ((unsigned)f2bf(wsrc[c * 128 + k + 1]) << 16);
    }
}

// ---------------------------------------------------------------------------
// 3-stage device-wide exclusive scan of cnt[VNUM] -> offs / fcursor / ccursor.
// ---------------------------------------------------------------------------
__device__ __forceinline__ int wave_incl_scan(int v, int lane) {
#pragma unroll
    for (int off = 1; off < 64; off <<= 1) {
        const int o = __shfl_up(v, off, 64);
        if (lane >= off) v += o;
    }
    return v;
}

__global__ __launch_bounds__(256) void scan_part_kernel(
    const int* __restrict__ cnt, int* __restrict__ partials)
{
    __shared__ int wsum[4];
    const int tid = threadIdx.x;
    const int i = blockIdx.x * 256 + tid;
    int v = (i < VNUM) ? cnt[i] : 0;
    const int lane = tid & 63, wave = tid >> 6;
#pragma unroll
    for (int off = 32; off > 0; off >>= 1) v += __shfl_down(v, off, 64);
    if (lane == 0) wsum[wave] = v;
    __syncthreads();
    if (tid == 0) partials[blockIdx.x] = wsum[0] + wsum[1] + wsum[2] + wsum[3];
}

__global__ __launch_bounds__(256) void scan_mid_kernel(
    const int* __restrict__ partials, int* __restrict__ blockoff,
    int* __restrict__ offs)
{
    __shared__ int wsum[4];
    const int tid = threadIdx.x;
    int v = (tid < SCAN_BLOCKS) ? partials[tid] : 0;
    const int lane = tid & 63, wave = tid >> 6;
    int inc = wave_incl_scan(v, lane);
    if (lane == 63) wsum[wave] = inc;
    __syncthreads();
    int woff = 0;
    for (int w2 = 0; w2 < wave; ++w2) woff += wsum[w2];
    if (tid < SCAN_BLOCKS) blockoff[tid] = woff + inc - v;
    if (tid == 0) offs[VNUM] = wsum[0] + wsum[1] + wsum[2] + wsum[3]; // NEDGE
}

__global__ __launch_bounds__(256) void scan_final_kernel(
    const int* __restrict__ cnt, const int* __restrict__ blockoff,
    int* __restrict__ offs, int* __restrict__ fcursor, int* __restrict__ ccursor)
{
    __shared__ int wsum[4];
    const int tid = threadIdx.x;
    const int i = blockIdx.x * 256 + tid;
    const int v = (i < VNUM) ? cnt[i] : 0;
    const int lane = tid & 63, wave = tid >> 6;
    const int inc = wave_incl_scan(v, lane);
    if (lane == 63) wsum[wave] = inc;
    __syncthreads();
    int woff = blockoff[blockIdx.x];
    for (int w2 = 0; w2 < wave; ++w2) woff += wsum[w2];
    if (i < VNUM) {
        const int e = woff + inc - v;
        offs[i] = e; fcursor[i] = e;
        if ((i & 1023) == 0) ccursor[i >> 10] = e;   // coarse segment start
    }
}

// ---------------------------------------------------------------------------
// Pass A: coarse partition into 49 bins (tidx>>10) via LDS staging +
// bulk-reserved contiguous runs.  rec = { sidx<<16 | bf16(w), tidx }
// ---------------------------------------------------------------------------
__global__ __launch_bounds__(256) void coarse_kernel(
    const int* __restrict__ sidx, const int* __restrict__ tidx,
    const float* __restrict__ enorm, const float* __restrict__ esgn,
    int* __restrict__ ccursor, uint2* __restrict__ coarse8)
{
    __shared__ uint2 lrec[CHUNK];      // 16 KB
    __shared__ int lcnt[4][NCB];
    __shared__ int lbase[4][NCB];
    __shared__ int loffs[NCB];
    __shared__ int grun[NCB];

    const int tid = threadIdx.x, lane = tid & 63, wv = tid >> 6;
    const int base = blockIdx.x * CHUNK;
    const int n = min(CHUNK, NEDGE - base);

    for (int i = tid; i < 4 * NCB; i += 256) (&lcnt[0][0])[i] = 0;
    __syncthreads();

    uint2 rec[8];
#pragma unroll
    for (int j = 0; j < 8; ++j) {
        const int e = base + j * 256 + tid;
        if (e < NEDGE) {
            const int t = tidx[e];
            const float w = esgn[e] * enorm[e];
            rec[j].x = ((unsigned)sidx[e] << 16) | (unsigned)f2bf(w);
            rec[j].y = (unsigned)t;
            atomicAdd(&lcnt[wv][t >> 10], 1);
        }
    }
    __syncthreads();

    if (tid < 64) {
        int c0 = 0, c1 = 0, c2 = 0, c3 = 0, tot = 0;
        if (lane < NCB) {
            c0 = lcnt[0][lane]; c1 = lcnt[1][lane];
            c2 = lcnt[2][lane]; c3 = lcnt[3][lane];
            tot = c0 + c1 + c2 + c3;
        }
        const int inc = wave_incl_scan(tot, lane);
        const int ex = inc - tot;
        if (lane < NCB) {
            loffs[lane]    = ex;
            lbase[0][lane] = ex;
            lbase[1][lane] = ex + c0;
            lbase[2][lane] = ex + c0 + c1;
            lbase[3][lane] = ex + c0 + c1 + c2;
            grun[lane] = atomicAdd(&ccursor[lane], tot);
        }
    }
    __syncthreads();

#pragma unroll
    for (int j = 0; j < 8; ++j) {
        const int e = base + j * 256 + tid;
        if (e < NEDGE) {
            const int cb = (int)(rec[j].y >> 10);
            const int pos = atomicAdd(&lbase[wv][cb], 1);
            lrec[pos] = rec[j];
        }
    }
    __syncthreads();

    for (int i = tid; i < n; i += 256) {
        const uint2 r = lrec[i];
        const int cb = (int)(r.y >> 10);
        coarse8[grun[cb] + (i - loffs[cb])] = r;
    }
}

// ---------------------------------------------------------------------------
// Pass B: fine scatter within ~130 KB coarse-bin windows (L2-resident).
// ---------------------------------------------------------------------------
__global__ __launch_bounds__(256) void fine_kernel(
    const uint2* __restrict__ coarse8, int* __restrict__ fcursor,
    unsigned int* __restrict__ pairs)
{
    const int i = blockIdx.x * 256 + threadIdx.x;
    const uint2 r = coarse8[i];
    const int pos = atomicAdd(&fcursor[(int)r.y], 1);
    pairs[pos] = r.x;
}

// ---------------------------------------------------------------------------
// aggregate: one wave per vertex, lane covers cols (2l, 2l+1). 256 B
// coalesced bf16-row gathers, unroll-4, float2 store.
// ---------------------------------------------------------------------------
__global__ __launch_bounds__(256) void aggregate_kernel(
    const int* __restrict__ offs, const unsigned int* __restrict__ pairs,
    const unsigned int* __restrict__ vrepr16, float* __restrict__ acc)
{
    const int v = blockIdx.x * 4 + (threadIdx.x >> 6);
    const int l = threadIdx.x & 63;
    int i = offs[v];
    const int end = offs[v + 1];

    float a0 = 0.0f, a1 = 0.0f;
    for (; i + 4 <= end; i += 4) {
        const unsigned p0 = pairs[i], p1 = pairs[i + 1];
        const unsigned p2 = pairs[i + 2], p3 = pairs[i + 3];
        const unsigned r0 = vrepr16[(size_t)(p0 >> 16) * 64 + l];
        const unsigned r1 = vrepr16[(size_t)(p1 >> 16) * 64 + l];
        const unsigned r2 = vrepr16[(size_t)(p2 >> 16) * 64 + l];
        const unsigned r3 = vrepr16[(size_t)(p3 >> 16) * 64 + l];
        const float w0 = bf16_lo(p0), w1 = bf16_lo(p1);
        const float w2 = bf16_lo(p2), w3 = bf16_lo(p3);
        a0 = fmaf(bf16_lo(r0), w0, a0); a1 = fmaf(bf16_hi(r0), w0, a1);
        a0 = fmaf(bf16_lo(r1), w1, a0); a1 = fmaf(bf16_hi(r1), w1, a1);
        a0 = fmaf(bf16_lo(r2), w2, a0); a1 = fmaf(bf16_hi(r2), w2, a1);
        a0 = fmaf(bf16_lo(r3), w3, a0); a1 = fmaf(bf16_hi(r3), w3, a1);
    }
    for (; i < end; ++i) {
        const unsigned p = pairs[i];
        const unsigned r = vrepr16[(size_t)(p >> 16) * 64 + l];
        const float w = bf16_lo(p);
        a0 = fmaf(bf16_lo(r), w, a0); a1 = fmaf(bf16_hi(r), w, a1);
    }
    *reinterpret_cast<float2*>(acc + (size_t)v * OUTF + 2 * l) = make_float2(a0, a1);
}

// ---------------------------------------------------------------------------
// gemm via MFMA 16x16x32 bf16. Block = 16 rows x 256 cols (2 heads x 128).
// Wave w owns col-tiles w*4..w*4+3; B-frags preloaded from d_ws (L2).
// A staged as bf16 LDS tile (pad 136 -> ds_read_b128 2-way banked = free).
// C/D layout: col = lane&15, row = (lane>>4)*4 + reg   [m89-verified].
// ---------------------------------------------------------------------------
__global__ __launch_bounds__(256) void gemm_mfma_kernel(
    const float* acc, const unsigned int* __restrict__ bfrag,
    const float* __restrict__ loc_b, const float* __restrict__ std_b,
    float* out)
{
    __shared__ unsigned short tile[16][136];   // bf16, padded (4.25 KB)
    const int t = threadIdx.x;
    const int row0 = blockIdx.x * 16;
    const int l = t & 63, w = t >> 6;

    // preload B fragments: 16 x 16B per wave (L2-resident)
    short8 bfr[4][4];
#pragma unroll
    for (int ct = 0; ct < 4; ++ct)
#pragma unroll
        for (int ks = 0; ks < 4; ++ks)
            bfr[ct][ks] = *reinterpret_cast<const short8*>(
                bfrag + ((((w * 4 + ct) * 4 + ks) * 64 + l) << 2));

    // stage 16x128 f32 -> bf16 tile (thread t: 8 consecutive floats)
    {
        const float* src = acc + (size_t)row0 * OUTF + t * 8;
        const float4 v0 = *reinterpret_cast<const float4*>(src);
        const float4 v1 = *reinterpret_cast<const float4*>(src + 4);
        uint4 pk;
        pk.x = (unsigned)f2bf(v0.x) | ((unsigned)f2bf(v0.y) << 16);
        pk.y = (unsigned)f2bf(v0.z) | ((unsigned)f2bf(v0.w) << 16);
        pk.z = (unsigned)f2bf(v1.x) | ((unsigned)f2bf(v1.y) << 16);
        pk.w = (unsigned)f2bf(v1.z) | ((unsigned)f2bf(v1.w) << 16);
        *reinterpret_cast<uint4*>(&tile[t >> 4][(t & 15) * 8]) = pk;
    }
    __syncthreads();

    const int m = l & 15, q = l >> 4;
    v4f accv[4];
#pragma unroll
    for (int ct = 0; ct < 4; ++ct) accv[ct] = (v4f){0.0f, 0.0f, 0.0f, 0.0f};

#pragma unroll
    for (int ks = 0; ks < 4; ++ks) {
        const short8 a = *reinterpret_cast<const short8*>(&tile[m][ks * 32 + q * 8]);
#pragma unroll
        for (int ct = 0; ct < 4; ++ct)
            accv[ct] = __builtin_amdgcn_mfma_f32_16x16x32_bf16(
                a, bfr[ct][ks], accv[ct], 0, 0, 0);
    }

    // epilogue: head is wave-uniform (w<2 -> loc, w>=2 -> std)
#pragma unroll
    for (int ct = 0; ct < 4; ++ct) {
        const int colg = (w * 4 + ct) * 16 + m;
        const int h = colg >> 7, c = colg & 127;
        const float bias = (h ? std_b : loc_b)[c];
        float* dst = out + (h ? (size_t)VNUM * OUTF : (size_t)0);
#pragma unroll
        for (int reg = 0; reg < 4; ++reg) {
            const int row = row0 + q * 4 + reg;
            float x = accv[ct][reg] + bias;
            if (h) x = fmaxf(x, 0.0f) + log1pf(expf(-fabsf(x))) + EPSF;
            dst[(size_t)row * OUTF + c] = x;
        }
    }
}

// Fallback gemm (no workspace): f32 vector path.
__global__ __launch_bounds__(256) void gemm_fallback_kernel(
    const float* acc,
    const float* __restrict__ loc_w, const float* __restrict__ loc_b,
    const float* __restrict__ std_w, const float* __restrict__ std_b,
    float* out)
{
    __shared__ float tile[16][OUTF];
    const int t = threadIdx.x;
    const int row0 = blockIdx.x * 16;
    {
        const float4* src = reinterpret_cast<const float4*>(acc + (size_t)row0 * OUTF);
        float4* dst = reinterpret_cast<float4*>(&tile[0][0]);
        dst[t] = src[t]; dst[t + 256] = src[t + 256];
    }
    __syncthreads();
    const int is_std = t >> 7;
    const int c = t & 127;
    const float* w = (is_std ? std_w : loc_w) + (size_t)c * OUTF;
    const float bias = is_std ? std_b[c] : loc_b[c];
    float accv[16];
#pragma unroll
    for (int r = 0; r < 16; ++r) accv[r] = 0.0f;
    for (int k = 0; k < OUTF; k += 4) {
        const float4 wv = *reinterpret_cast<const float4*>(w + k);
#pragma unroll
        for (int r = 0; r < 16; ++r) {
            const float4 pv = *reinterpret_cast<const float4*>(&tile[r][k]);
            float a = accv[r];
            a = fmaf(pv.x, wv.x, a); a = fmaf(pv.y, wv.y, a);
            a = fmaf(pv.z, wv.z, a); a = fmaf(pv.w, wv.w, a);
            accv[r] = a;
        }
    }
    float* dst_base = out + (is_std ? (size_t)VNUM * OUTF : (size_t)0);
#pragma unroll
    for (int r = 0; r < 16; ++r) {
        const float x = accv[r] + bias;
        dst_base[(size_t)(row0 + r) * OUTF + c] =
            is_std ? (fmaxf(x, 0.0f) + log1pf(expf(-fabsf(x))) + EPSF) : x;
    }
}

extern "C" void kernel_launch(void* const* d_in, const int* in_sizes, int n_in,
                              void* d_out, int out_size, void* d_ws, size_t ws_size,
                              hipStream_t stream) {
    const int*   sidx  = (const int*)  d_in[0];
    const int*   tidx  = (const int*)  d_in[1];
    const float* enorm = (const float*)d_in[2];
    const float* esgn  = (const float*)d_in[3];
    const float* vrepr = (const float*)d_in[4];
    const float* loc_w = (const float*)d_in[5];
    const float* loc_b = (const float*)d_in[6];
    const float* std_w = (const float*)d_in[7];
    const float* std_b = (const float*)d_in[8];

    float* out = (float*)d_out;
    float* acc = out;   // loc half: coarse8 first, then segment sums (acc)

    // coarse8 (12.8 MB) borrows the loc half; dead before aggregate writes acc.
    uint2* coarse8 = (uint2*)out;

    // std-half scratch: pairs 1.6M | vrepr16 3.2M | cnt 50K | offs 50K+1 |
    // fcursor 50K | ccursor 49 | partials 196 | blockoff 196  (~4.95M words)
    unsigned int* sbase   = (unsigned int*)(out + (size_t)VNUM * OUTF);
    unsigned int* pairs   = sbase;
    unsigned int* vrepr16 = sbase + NEDGE;
    int* cnt      = (int*)(sbase + NEDGE + (size_t)VNUM * 64);
    int* offs     = cnt + VNUM;
    int* fcursor  = offs + VNUM + 1;
    int* ccursor  = fcursor + VNUM;
    int* partials = ccursor + NCB;
    int* blockoff = partials + SCAN_BLOCKS;

    const bool use_ws = ws_size >= 16384 * sizeof(unsigned int);  // 64 KB
    unsigned int* bfrag = use_ws ? (unsigned int*)d_ws : nullptr;

    hipMemsetAsync(cnt, 0, VNUM * sizeof(int), stream);

    const int prep_blocks = CONV_BLOCKS + HIST_BLOCKS + (use_ws ? BFRAG_BLOCKS : 0);
    prep_kernel      <<<prep_blocks, 256, 0, stream>>>(vrepr, vrepr16, tidx, cnt,
                                                       loc_w, std_w, bfrag);
    scan_part_kernel <<<SCAN_BLOCKS, 256, 0, stream>>>(cnt, partials);
    scan_mid_kernel  <<<1,           256, 0, stream>>>(partials, blockoff, offs);
    scan_final_kernel<<<SCAN_BLOCKS, 256, 0, stream>>>(cnt, blockoff, offs,
                                                       fcursor, ccursor);
    coarse_kernel    <<<COARSE_BLOCKS, 256, 0, stream>>>(sidx, tidx, enorm, esgn,
                                                         ccursor, coarse8);
    fine_kernel      <<<NEDGE / 256, 256, 0, stream>>>(coarse8, fcursor, pairs);
    aggregate_kernel <<<VNUM / 4,    256, 0, stream>>>(offs, pairs, vrepr16, acc);

    if (use_ws) {
        gemm_mfma_kernel<<<VNUM / 16, 256, 0, stream>>>(acc, bfrag, loc_b, std_b, out);
    } else {
        gemm_fallback_kernel<<<VNUM / 16, 256, 0, stream>>>(acc, loc_w, loc_b,
                                                            std_w, std_b, out);
    }
}

// Round 8
// 270.852 us; speedup vs baseline: 5.1155x; 1.2902x over previous
//
#include <hip/hip_runtime.h>
#include <math.h>

#define VNUM 50000
#define OUTF 128
#define NEDGE 1600000
#define EPSF 1e-7f

#define CONV_BLOCKS 6250    // 50000*128 / (256*4)
#define BFRAG_BLOCKS 64     // 16384 uint pairs / 256

#define CHUNK 2048          // edges per coarse/hist block
#define NCB 49              // coarse bins: tidx>>10 (1024 vertices/bin)
#define COARSE_BLOCKS 782   // ceil(NEDGE/CHUNK)
#define SUBS 8              // sub-blocks per bin for binhist/fine
#define NSB (NCB * SUBS)    // 392

typedef __attribute__((ext_vector_type(8))) short short8;
typedef __attribute__((ext_vector_type(4))) float v4f;

// ---------------------------------------------------------------------------
// bf16 helpers (RNE)
// ---------------------------------------------------------------------------
__device__ __forceinline__ unsigned short f2bf(float f) {
    union { float f; unsigned int u; } c; c.f = f;
    unsigned int u = c.u;
    return (unsigned short)((u + 0x7FFFu + ((u >> 16) & 1u)) >> 16);
}
__device__ __forceinline__ float bf16_lo(unsigned int p) {
    union { unsigned int u; float f; } c; c.u = p << 16; return c.f;
}
__device__ __forceinline__ float bf16_hi(unsigned int p) {
    union { unsigned int u; float f; } c; c.u = p & 0xFFFF0000u; return c.f;
}

__device__ __forceinline__ int wave_incl_scan(int v, int lane) {
#pragma unroll
    for (int off = 1; off < 64; off <<= 1) {
        const int o = __shfl_up(v, off, 64);
        if (lane >= off) v += o;
    }
    return v;
}

// ---------------------------------------------------------------------------
// prep: (a) vrepr f32 -> packed bf16x2, (b) 49-bin coarse hist (LDS-staged,
// 49 global atomics per 2048-edge block), (c) MFMA B-fragment build in d_ws.
// ---------------------------------------------------------------------------
__global__ __launch_bounds__(256) void prep_kernel(
    const float* __restrict__ vrepr, unsigned int* __restrict__ vrepr16,
    const int* __restrict__ tidx, int* __restrict__ chist,
    const float* __restrict__ loc_w, const float* __restrict__ std_w,
    unsigned int* bfrag)
{
    __shared__ int lc[4][NCB];
    const int b = blockIdx.x, tid = threadIdx.x;
    if (b < CONV_BLOCKS) {
        const size_t base = (size_t)b * 1024 + tid * 4;
        const float4 v = *reinterpret_cast<const float4*>(vrepr + base);
        uint2 o;
        o.x = (unsigned)f2bf(v.x) | ((unsigned)f2bf(v.y) << 16);
        o.y = (unsigned)f2bf(v.z) | ((unsigned)f2bf(v.w) << 16);
        *reinterpret_cast<uint2*>(vrepr16 + base / 2) = o;
    } else if (b < CONV_BLOCKS + COARSE_BLOCKS) {
        const int hb = b - CONV_BLOCKS;
        for (int i = tid; i < 4 * NCB; i += 256) (&lc[0][0])[i] = 0;
        __syncthreads();
        const int base = hb * CHUNK;
#pragma unroll
        for (int j = 0; j < 8; ++j) {
            const int e = base + j * 256 + tid;
            if (e < NEDGE) atomicAdd(&lc[tid >> 6][tidx[e] >> 10], 1);
        }
        __syncthreads();
        if (tid < NCB) {
            const int s = lc[0][tid] + lc[1][tid] + lc[2][tid] + lc[3][tid];
            if (s) atomicAdd(&chist[tid], s);
        }
    } else {
        const int p = (b - (CONV_BLOCKS + COARSE_BLOCKS)) * 256 + tid; // 0..16383
        const int j2 = p & 3, lq = (p >> 2) & 63, ks = (p >> 8) & 3, ct = p >> 10;
        const int k = ks * 32 + (lq >> 4) * 8 + j2 * 2;
        const int n = ct * 16 + (lq & 15);
        const float* wsrc = (n >> 7) ? std_w : loc_w;
        const int c = n & 127;
        bfrag[p] = (unsigned)f2bf(wsrc[c * 128 + k]) |
                   ((unsigned)f2bf(wsrc[c * 128 + k + 1]) << 16);
    }
}

// ---------------------------------------------------------------------------
// scan_coarse: single wave scans 49 bin counts -> cbase[50] + ccursor copy;
// also seeds offs[VNUM] = NEDGE.
// ---------------------------------------------------------------------------
__global__ __launch_bounds__(64) void scan_coarse_kernel(
    const int* __restrict__ chist, int* __restrict__ cbase,
    int* __restrict__ ccursor, int* __restrict__ offs)
{
    const int tid = threadIdx.x;
    const int v = (tid < NCB) ? chist[tid] : 0;
    const int inc = wave_incl_scan(v, tid);
    const int ex = inc - v;
    if (tid < NCB) { cbase[tid] = ex; ccursor[tid] = ex; }
    if (tid == NCB - 1) { cbase[NCB] = inc; offs[VNUM] = inc; }  // == NEDGE
}

// ---------------------------------------------------------------------------
// coarse: partition edges into 49 bin segments via LDS staging + bulk-
// reserved contiguous runs. rec = { sidx<<16 | bf16(w), tidx }
// ---------------------------------------------------------------------------
__global__ __launch_bounds__(256) void coarse_kernel(
    const int* __restrict__ sidx, const int* __restrict__ tidx,
    const float* __restrict__ enorm, const float* __restrict__ esgn,
    int* __restrict__ ccursor, uint2* __restrict__ coarse8)
{
    __shared__ uint2 lrec[CHUNK];      // 16 KB
    __shared__ int lcnt[4][NCB];
    __shared__ int lbase[4][NCB];
    __shared__ int loffs[NCB];
    __shared__ int grun[NCB];

    const int tid = threadIdx.x, lane = tid & 63, wv = tid >> 6;
    const int base = blockIdx.x * CHUNK;
    const int n = min(CHUNK, NEDGE - base);

    for (int i = tid; i < 4 * NCB; i += 256) (&lcnt[0][0])[i] = 0;
    __syncthreads();

    uint2 rec[8];
#pragma unroll
    for (int j = 0; j < 8; ++j) {
        const int e = base + j * 256 + tid;
        if (e < NEDGE) {
            const int t = tidx[e];
            const float w = esgn[e] * enorm[e];
            rec[j].x = ((unsigned)sidx[e] << 16) | (unsigned)f2bf(w);
            rec[j].y = (unsigned)t;
            atomicAdd(&lcnt[wv][t >> 10], 1);
        }
    }
    __syncthreads();

    if (tid < 64) {
        int c0 = 0, c1 = 0, c2 = 0, c3 = 0, tot = 0;
        if (lane < NCB) {
            c0 = lcnt[0][lane]; c1 = lcnt[1][lane];
            c2 = lcnt[2][lane]; c3 = lcnt[3][lane];
            tot = c0 + c1 + c2 + c3;
        }
        const int inc = wave_incl_scan(tot, lane);
        const int ex = inc - tot;
        if (lane < NCB) {
            loffs[lane]    = ex;
            lbase[0][lane] = ex;
            lbase[1][lane] = ex + c0;
            lbase[2][lane] = ex + c0 + c1;
            lbase[3][lane] = ex + c0 + c1 + c2;
            grun[lane] = atomicAdd(&ccursor[lane], tot);
        }
    }
    __syncthreads();

#pragma unroll
    for (int j = 0; j < 8; ++j) {
        const int e = base + j * 256 + tid;
        if (e < NEDGE) {
            const int cb = (int)(rec[j].y >> 10);
            const int pos = atomicAdd(&lbase[wv][cb], 1);
            lrec[pos] = rec[j];
        }
    }
    __syncthreads();

    for (int i = tid; i < n; i += 256) {
        const uint2 r = lrec[i];
        const int cb = (int)(r.y >> 10);
        coarse8[grun[cb] + (i - loffs[cb])] = r;
    }
}

// ---------------------------------------------------------------------------
// binhist: block (bin,sub) histograms its slice of the bin's records into
// 1024 LDS counters, writes them coalesced to bcnt (no global atomics).
// ---------------------------------------------------------------------------
__global__ __launch_bounds__(256) void binhist_kernel(
    const uint2* __restrict__ coarse8, const int* __restrict__ cbase,
    int* __restrict__ bcnt)
{
    __shared__ int lc[1024];
    const int tid = threadIdx.x;
    const int bin = blockIdx.x >> 3, sub = blockIdx.x & (SUBS - 1);
    for (int i = tid; i < 1024; i += 256) lc[i] = 0;
    __syncthreads();
    const int s0 = cbase[bin];
    const int L  = cbase[bin + 1] - s0;
    const int beg = s0 + (L * sub) / SUBS;
    const int end = s0 + (L * (sub + 1)) / SUBS;
    for (int i = beg + tid; i < end; i += 256)
        atomicAdd(&lc[coarse8[i].y & 1023], 1);
    __syncthreads();
    for (int i = tid; i < 1024; i += 256)
        bcnt[(blockIdx.x << 10) + i] = lc[i];
}

// ---------------------------------------------------------------------------
// scan_bin: one block per bin. Per-vertex exclusive scan of the bin's 1024
// totals -> offs; per-(sub,vertex) start cursors -> fcur. No atomics.
// ---------------------------------------------------------------------------
__global__ __launch_bounds__(256) void scan_bin_kernel(
    const int* __restrict__ bcnt, const int* __restrict__ cbase,
    int* __restrict__ offs, int* __restrict__ fcur)
{
    __shared__ int wsum[4];
    const int tid = threadIdx.x, lane = tid & 63, wv = tid >> 6;
    const int bin = blockIdx.x;
    const int i0 = tid * 4;

    int c[SUBS][4];
#pragma unroll
    for (int s = 0; s < SUBS; ++s) {
        const int base = ((bin * SUBS + s) << 10) + i0;
#pragma unroll
        for (int j = 0; j < 4; ++j) c[s][j] = bcnt[base + j];
    }
    int tot[4];
#pragma unroll
    for (int j = 0; j < 4; ++j) {
        int t2 = 0;
#pragma unroll
        for (int s = 0; s < SUBS; ++s) t2 += c[s][j];
        tot[j] = t2;
    }
    const int ts = tot[0] + tot[1] + tot[2] + tot[3];
    const int inc = wave_incl_scan(ts, lane);
    if (lane == 63) wsum[wv] = inc;
    __syncthreads();
    int run = cbase[bin] + (inc - ts);
    for (int w2 = 0; w2 < wv; ++w2) run += wsum[w2];

#pragma unroll
    for (int j = 0; j < 4; ++j) {
        const int v = (bin << 10) + i0 + j;
        if (v < VNUM) offs[v] = run;
        int p = run;
#pragma unroll
        for (int s = 0; s < SUBS; ++s) {
            fcur[((bin * SUBS + s) << 10) + i0 + j] = p;
            p += c[s][j];
        }
        run += tot[j];
    }
}

// ---------------------------------------------------------------------------
// fine: block (bin,sub) re-reads its slice, scatters payloads to exact CSR
// positions using LDS cursors (LDS int atomics only; writes stay in the
// bin's ~L2-resident window).
// ---------------------------------------------------------------------------
__global__ __launch_bounds__(256) void fine_kernel(
    const uint2* __restrict__ coarse8, const int* __restrict__ cbase,
    const int* __restrict__ fcur, unsigned int* __restrict__ pairs)
{
    __shared__ int lfc[1024];
    const int tid = threadIdx.x;
    const int bin = blockIdx.x >> 3, sub = blockIdx.x & (SUBS - 1);
    for (int i = tid; i < 1024; i += 256)
        lfc[i] = fcur[(blockIdx.x << 10) + i];
    __syncthreads();
    const int s0 = cbase[bin];
    const int L  = cbase[bin + 1] - s0;
    const int beg = s0 + (L * sub) / SUBS;
    const int end = s0 + (L * (sub + 1)) / SUBS;
    for (int i = beg + tid; i < end; i += 256) {
        const uint2 r = coarse8[i];
        const int pos = atomicAdd(&lfc[r.y & 1023], 1);
        pairs[pos] = r.x;
    }
}

// ---------------------------------------------------------------------------
// aggregate: one wave per vertex, lane covers cols (2l, 2l+1). 256 B
// coalesced bf16-row gathers, unroll-4, float2 store.
// ---------------------------------------------------------------------------
__global__ __launch_bounds__(256) void aggregate_kernel(
    const int* __restrict__ offs, const unsigned int* __restrict__ pairs,
    const unsigned int* __restrict__ vrepr16, float* __restrict__ acc)
{
    const int v = blockIdx.x * 4 + (threadIdx.x >> 6);
    const int l = threadIdx.x & 63;
    int i = offs[v];
    const int end = offs[v + 1];

    float a0 = 0.0f, a1 = 0.0f;
    for (; i + 4 <= end; i += 4) {
        const unsigned p0 = pairs[i], p1 = pairs[i + 1];
        const unsigned p2 = pairs[i + 2], p3 = pairs[i + 3];
        const unsigned r0 = vrepr16[(size_t)(p0 >> 16) * 64 + l];
        const unsigned r1 = vrepr16[(size_t)(p1 >> 16) * 64 + l];
        const unsigned r2 = vrepr16[(size_t)(p2 >> 16) * 64 + l];
        const unsigned r3 = vrepr16[(size_t)(p3 >> 16) * 64 + l];
        const float w0 = bf16_lo(p0), w1 = bf16_lo(p1);
        const float w2 = bf16_lo(p2), w3 = bf16_lo(p3);
        a0 = fmaf(bf16_lo(r0), w0, a0); a1 = fmaf(bf16_hi(r0), w0, a1);
        a0 = fmaf(bf16_lo(r1), w1, a0); a1 = fmaf(bf16_hi(r1), w1, a1);
        a0 = fmaf(bf16_lo(r2), w2, a0); a1 = fmaf(bf16_hi(r2), w2, a1);
        a0 = fmaf(bf16_lo(r3), w3, a0); a1 = fmaf(bf16_hi(r3), w3, a1);
    }
    for (; i < end; ++i) {
        const unsigned p = pairs[i];
        const unsigned r = vrepr16[(size_t)(p >> 16) * 64 + l];
        const float w = bf16_lo(p);
        a0 = fmaf(bf16_lo(r), w, a0); a1 = fmaf(bf16_hi(r), w, a1);
    }
    *reinterpret_cast<float2*>(acc + (size_t)v * OUTF + 2 * l) = make_float2(a0, a1);
}

// ---------------------------------------------------------------------------
// gemm via MFMA 16x16x32 bf16 (R7-proven).
// ---------------------------------------------------------------------------
__global__ __launch_bounds__(256) void gemm_mfma_kernel(
    const float* acc, const unsigned int* __restrict__ bfrag,
    const float* __restrict__ loc_b, const float* __restrict__ std_b,
    float* out)
{
    __shared__ unsigned short tile[16][136];   // bf16, padded
    const int t = threadIdx.x;
    const int row0 = blockIdx.x * 16;
    const int l = t & 63, w = t >> 6;

    short8 bfr[4][4];
#pragma unroll
    for (int ct = 0; ct < 4; ++ct)
#pragma unroll
        for (int ks = 0; ks < 4; ++ks)
            bfr[ct][ks] = *reinterpret_cast<const short8*>(
                bfrag + ((((w * 4 + ct) * 4 + ks) * 64 + l) << 2));

    {
        const float* src = acc + (size_t)row0 * OUTF + t * 8;
        const float4 v0 = *reinterpret_cast<const float4*>(src);
        const float4 v1 = *reinterpret_cast<const float4*>(src + 4);
        uint4 pk;
        pk.x = (unsigned)f2bf(v0.x) | ((unsigned)f2bf(v0.y) << 16);
        pk.y = (unsigned)f2bf(v0.z) | ((unsigned)f2bf(v0.w) << 16);
        pk.z = (unsigned)f2bf(v1.x) | ((unsigned)f2bf(v1.y) << 16);
        pk.w = (unsigned)f2bf(v1.z) | ((unsigned)f2bf(v1.w) << 16);
        *reinterpret_cast<uint4*>(&tile[t >> 4][(t & 15) * 8]) = pk;
    }
    __syncthreads();

    const int m = l & 15, q = l >> 4;
    v4f accv[4];
#pragma unroll
    for (int ct = 0; ct < 4; ++ct) accv[ct] = (v4f){0.0f, 0.0f, 0.0f, 0.0f};

#pragma unroll
    for (int ks = 0; ks < 4; ++ks) {
        const short8 a = *reinterpret_cast<const short8*>(&tile[m][ks * 32 + q * 8]);
#pragma unroll
        for (int ct = 0; ct < 4; ++ct)
            accv[ct] = __builtin_amdgcn_mfma_f32_16x16x32_bf16(
                a, bfr[ct][ks], accv[ct], 0, 0, 0);
    }

#pragma unroll
    for (int ct = 0; ct < 4; ++ct) {
        const int colg = (w * 4 + ct) * 16 + m;
        const int h = colg >> 7, c = colg & 127;
        const float bias = (h ? std_b : loc_b)[c];
        float* dst = out + (h ? (size_t)VNUM * OUTF : (size_t)0);
#pragma unroll
        for (int reg = 0; reg < 4; ++reg) {
            const int row = row0 + q * 4 + reg;
            float x = accv[ct][reg] + bias;
            if (h) x = fmaxf(x, 0.0f) + log1pf(expf(-fabsf(x))) + EPSF;
            dst[(size_t)row * OUTF + c] = x;
        }
    }
}

// Fallback gemm (no workspace): f32 vector path.
__global__ __launch_bounds__(256) void gemm_fallback_kernel(
    const float* acc,
    const float* __restrict__ loc_w, const float* __restrict__ loc_b,
    const float* __restrict__ std_w, const float* __restrict__ std_b,
    float* out)
{
    __shared__ float tile[16][OUTF];
    const int t = threadIdx.x;
    const int row0 = blockIdx.x * 16;
    {
        const float4* src = reinterpret_cast<const float4*>(acc + (size_t)row0 * OUTF);
        float4* dst = reinterpret_cast<float4*>(&tile[0][0]);
        dst[t] = src[t]; dst[t + 256] = src[t + 256];
    }
    __syncthreads();
    const int is_std = t >> 7;
    const int c = t & 127;
    const float* w = (is_std ? std_w : loc_w) + (size_t)c * OUTF;
    const float bias = is_std ? std_b[c] : loc_b[c];
    float accv[16];
#pragma unroll
    for (int r = 0; r < 16; ++r) accv[r] = 0.0f;
    for (int k = 0; k < OUTF; k += 4) {
        const float4 wv = *reinterpret_cast<const float4*>(w + k);
#pragma unroll
        for (int r = 0; r < 16; ++r) {
            const float4 pv = *reinterpret_cast<const float4*>(&tile[r][k]);
            float a = accv[r];
            a = fmaf(pv.x, wv.x, a); a = fmaf(pv.y, wv.y, a);
            a = fmaf(pv.z, wv.z, a); a = fmaf(pv.w, wv.w, a);
            accv[r] = a;
        }
    }
    float* dst_base = out + (is_std ? (size_t)VNUM * OUTF : (size_t)0);
#pragma unroll
    for (int r = 0; r < 16; ++r) {
        const float x = accv[r] + bias;
        dst_base[(size_t)(row0 + r) * OUTF + c] =
            is_std ? (fmaxf(x, 0.0f) + log1pf(expf(-fabsf(x))) + EPSF) : x;
    }
}

extern "C" void kernel_launch(void* const* d_in, const int* in_sizes, int n_in,
                              void* d_out, int out_size, void* d_ws, size_t ws_size,
                              hipStream_t stream) {
    const int*   sidx  = (const int*)  d_in[0];
    const int*   tidx  = (const int*)  d_in[1];
    const float* enorm = (const float*)d_in[2];
    const float* esgn  = (const float*)d_in[3];
    const float* vrepr = (const float*)d_in[4];
    const float* loc_w = (const float*)d_in[5];
    const float* loc_b = (const float*)d_in[6];
    const float* std_w = (const float*)d_in[7];
    const float* std_b = (const float*)d_in[8];

    float* out = (float*)d_out;
    float* acc = out;   // loc half: coarse8 first, then segment sums (acc)

    // coarse8 (12.8 MB) borrows the loc half; dead before aggregate writes acc.
    uint2* coarse8 = (uint2*)out;

    // std-half scratch (6.4M words):
    //   pairs 1.6M | vrepr16 3.2M | bcnt 392K | fcur 392K | offs 50001 |
    //   cbase 50 | ccursor 49 | chist 49   total ~5.66M
    unsigned int* sbase   = (unsigned int*)(out + (size_t)VNUM * OUTF);
    unsigned int* pairs   = sbase;
    unsigned int* vrepr16 = sbase + NEDGE;
    int* bcnt    = (int*)(sbase + NEDGE + (size_t)VNUM * 64);
    int* fcur    = bcnt + NSB * 1024;
    int* offs    = fcur + NSB * 1024;
    int* cbase   = offs + VNUM + 1;
    int* ccursor = cbase + NCB + 1;
    int* chist   = ccursor + NCB;

    const bool use_ws = ws_size >= 16384 * sizeof(unsigned int);  // 64 KB
    unsigned int* bfrag = use_ws ? (unsigned int*)d_ws : nullptr;

    hipMemsetAsync(chist, 0, NCB * sizeof(int), stream);

    const int prep_blocks = CONV_BLOCKS + COARSE_BLOCKS + (use_ws ? BFRAG_BLOCKS : 0);
    prep_kernel       <<<prep_blocks, 256, 0, stream>>>(vrepr, vrepr16, tidx, chist,
                                                        loc_w, std_w, bfrag);
    scan_coarse_kernel<<<1, 64, 0, stream>>>(chist, cbase, ccursor, offs);
    coarse_kernel     <<<COARSE_BLOCKS, 256, 0, stream>>>(sidx, tidx, enorm, esgn,
                                                          ccursor, coarse8);
    binhist_kernel    <<<NSB, 256, 0, stream>>>(coarse8, cbase, bcnt);
    scan_bin_kernel   <<<NCB, 256, 0, stream>>>(bcnt, cbase, offs, fcur);
    fine_kernel       <<<NSB, 256, 0, stream>>>(coarse8, cbase, fcur, pairs);
    aggregate_kernel  <<<VNUM / 4, 256, 0, stream>>>(offs, pairs, vrepr16, acc);

    if (use_ws) {
        gemm_mfma_kernel<<<VNUM / 16, 256, 0, stream>>>(acc, bfrag, loc_b, std_b, out);
    } else {
        gemm_fallback_kernel<<<VNUM / 16, 256, 0, stream>>>(acc, loc_w, loc_b,
                                                            std_w, std_b, out);
    }
}